// Round 1
// baseline (471.451 us; speedup 1.0000x reference)
//
#include <hip/hip_runtime.h>

// ---------------- problem constants ----------------
#define B2    2
#define NSEQ  2048
#define DM    512
#define NH    8
#define DK    64
#define MROWS 4096            // B2*NSEQ
#define BH    (B2*NH)         // 16
#define BHSTR (NSEQ*DK)       // 131072 elements per (b,h) slab
#define EPSF  1e-8f
#define OUT0  (MROWS*DM)      // 2097152 floats: start of attention region in d_out

typedef __attribute__((ext_vector_type(8))) short short8;
typedef __attribute__((ext_vector_type(4))) float f32x4;

union S8 { short8 v; short s[8]; };
union F4 { f32x4 v; float f[4]; };

// ---------------- static device scratch (~42 MB) ----------------
__device__ float          g_Qp[MROWS*DM];    // [bh][n][d] elu(Q)+1, fp32 (un-normalized; qinv folded later)
__device__ float          g_Kn[MROWS*DM];    // [bh][n][d] elu(K)+1, then normalized in-place
__device__ float          g_Vh[MROWS*DM];    // [bh][n][d]
__device__ float          g_OH[MROWS*DM];    // [b][n][h*64+d] out-heads (pre final projection)
__device__ unsigned short g_Qbf[MROWS*DM];   // bf16 of g_Qp
__device__ unsigned short g_Kbf[MROWS*DM];   // bf16 of normalized g_Kn
__device__ float          g_qinv[BH*NSEQ];   // 1/(row-sum + eps)
__device__ float          g_ksum[BH*DK];     // column sums of K (atomic)
__device__ float          g_KV[BH*DK*DK];    // Kn^T V  (atomic)

// ---------------- helpers ----------------
__device__ inline unsigned short f2bf(float x) {
    union { float f; unsigned u; } v; v.f = x;
    unsigned r = v.u + 0x7fffu + ((v.u >> 16) & 1u);   // RNE
    return (unsigned short)(r >> 16);
}
__device__ inline float bf2f(unsigned short h) {
    union { unsigned u; float f; } v; v.u = ((unsigned)h) << 16; return v.f;
}
__device__ inline f32x4 mfma_bf16(short8 a, short8 b, f32x4 c) {
    return __builtin_amdgcn_mfma_f32_16x16x32_bf16(a, b, c, 0, 0, 0);
}

// ---------------- zero the atomic accumulators ----------------
__global__ void zero_small() {
    int i = blockIdx.x * 256 + threadIdx.x;
    if (i < BH*DK*DK) g_KV[i] = 0.f;
    if (i < BH*DK)    g_ksum[i] = 0.f;
}

// ---------------- split-bf16 MFMA GEMM: C[m,n] = sum_k A[m,k]*W[n,k] + bias[n] ----------------
// M=4096, N=512, K=512. Tile 128(M) x 64(N), BK=32. grid (32,8), block 256 (4 waves).
// mode 0: Q -> elu+1 -> g_Qp + g_Qbf ; mode 1: K -> elu+1 -> g_Kn ; mode 2: V -> g_Vh ;
// mode 3: A = g_OH (arg ignored), out -> dout[m*512+n]
__global__ __launch_bounds__(256) void gemm_split(const float* __restrict__ A,
                                                  const float* __restrict__ W,
                                                  const float* __restrict__ bias,
                                                  float* __restrict__ dout, int mode) {
    // LDS stride 56 shorts = 112 B (16B-aligned rows, 2-way-bank-free fragment reads)
    __shared__ short Ah[128*56], Al[128*56], Bh_s[64*56], Bl_s[64*56];

    const float* Ap = (mode == 3) ? (const float*)g_OH : A;

    int t = threadIdx.x;
    int m0 = blockIdx.x * 128, n0 = blockIdx.y * 64;
    int lane = t & 63, w = t >> 6;
    int l15 = lane & 15, quad = lane >> 4;

    f32x4 acc[2][4];
    f32x4 z4 = {0.f, 0.f, 0.f, 0.f};
#pragma unroll
    for (int i = 0; i < 2; i++)
#pragma unroll
        for (int j = 0; j < 4; j++) acc[i][j] = z4;

    int ar = t >> 1, ac = (t & 1) * 16;   // A stage: row, col0 (16 elems)
    int br = t >> 2, bc = (t & 3) * 8;    // B stage: row, col0 (8 elems)

    for (int k0 = 0; k0 < 512; k0 += 32) {
        // ---- stage A tile 128x32 (fp32 -> hi/lo bf16) ----
        {
            const float* ag = Ap + (size_t)(m0 + ar) * 512 + k0 + ac;
            float xv[16];
            *(f32x4*)&xv[0]  = *(const f32x4*)(ag + 0);
            *(f32x4*)&xv[4]  = *(const f32x4*)(ag + 4);
            *(f32x4*)&xv[8]  = *(const f32x4*)(ag + 8);
            *(f32x4*)&xv[12] = *(const f32x4*)(ag + 12);
            S8 h0, h1, l0, l1;
#pragma unroll
            for (int i = 0; i < 8; i++) {
                float x = xv[i];
                unsigned short hb = f2bf(x);
                h0.s[i] = (short)hb;
                l0.s[i] = (short)f2bf(x - bf2f(hb));
            }
#pragma unroll
            for (int i = 0; i < 8; i++) {
                float x = xv[8 + i];
                unsigned short hb = f2bf(x);
                h1.s[i] = (short)hb;
                l1.s[i] = (short)f2bf(x - bf2f(hb));
            }
            *(short8*)&Ah[ar*56 + ac]     = h0.v;
            *(short8*)&Ah[ar*56 + ac + 8] = h1.v;
            *(short8*)&Al[ar*56 + ac]     = l0.v;
            *(short8*)&Al[ar*56 + ac + 8] = l1.v;
        }
        // ---- stage B tile 64x32 ----
        {
            const float* wg = W + (size_t)(n0 + br) * 512 + k0 + bc;
            float xv[8];
            *(f32x4*)&xv[0] = *(const f32x4*)(wg + 0);
            *(f32x4*)&xv[4] = *(const f32x4*)(wg + 4);
            S8 h0, l0;
#pragma unroll
            for (int i = 0; i < 8; i++) {
                float x = xv[i];
                unsigned short hb = f2bf(x);
                h0.s[i] = (short)hb;
                l0.s[i] = (short)f2bf(x - bf2f(hb));
            }
            *(short8*)&Bh_s[br*56 + bc] = h0.v;
            *(short8*)&Bl_s[br*56 + bc] = l0.v;
        }
        __syncthreads();

        // ---- compute: wave w owns rows [w*32, w*32+32), all 64 cols ----
        int koff = quad * 8;
        short8 a_h[2], a_l[2], b_h[4], b_l[4];
#pragma unroll
        for (int i = 0; i < 2; i++) {
            int rr = (w*32 + i*16 + l15) * 56 + koff;
            a_h[i] = *(const short8*)&Ah[rr];
            a_l[i] = *(const short8*)&Al[rr];
        }
#pragma unroll
        for (int j = 0; j < 4; j++) {
            int rr = (j*16 + l15) * 56 + koff;
            b_h[j] = *(const short8*)&Bh_s[rr];
            b_l[j] = *(const short8*)&Bl_s[rr];
        }
#pragma unroll
        for (int i = 0; i < 2; i++)
#pragma unroll
            for (int j = 0; j < 4; j++) {
                acc[i][j] = mfma_bf16(a_h[i], b_h[j], acc[i][j]);
                acc[i][j] = mfma_bf16(a_h[i], b_l[j], acc[i][j]);
                acc[i][j] = mfma_bf16(a_l[i], b_h[j], acc[i][j]);
            }
        __syncthreads();
    }

    // ---- epilogue ----
#pragma unroll
    for (int j = 0; j < 4; j++) {
        int col = n0 + j*16 + l15;
        float bs = bias[col];
#pragma unroll
        for (int i = 0; i < 2; i++) {
            F4 v; v.v = acc[i][j];
#pragma unroll
            for (int r = 0; r < 4; r++) {
                int row = m0 + w*32 + i*16 + quad*4 + r;
                float val = v.f[r] + bs;
                if (mode == 3) {
                    dout[(size_t)row * 512 + col] = val;
                } else {
                    int bb = row >> 11, nn = row & 2047;
                    int hh = col >> 6,  dd = col & 63;
                    int dst = (bb*8 + hh) * BHSTR + nn*64 + dd;
                    if (mode == 2) {
                        g_Vh[dst] = val;
                    } else {
                        float e = (val > 0.f) ? (val + 1.f) : expf(val);
                        if (mode == 0) { g_Qp[dst] = e; g_Qbf[dst] = f2bf(e); }
                        else           { g_Kn[dst] = e; }
                    }
                }
            }
        }
    }
}

// ---------------- qinv: 1/(sum_d Q + eps), one wave per row ----------------
__global__ void qsum_kernel() {
    int t = threadIdx.x, w = t >> 6, lane = t & 63;
    int row = blockIdx.x * 4 + w;                 // [0, 32768)
    float v = g_Qp[(size_t)row * 64 + lane];
#pragma unroll
    for (int off = 32; off; off >>= 1) v += __shfl_down(v, off, 64);
    if (lane == 0) g_qinv[row] = 1.f / (v + EPSF);
}

// ---------------- ksum: column sums of K over n (atomic partials) ----------------
__global__ void ksum_kernel() {
    int t = threadIdx.x;
    int bh = blockIdx.x >> 3, part = blockIdx.x & 7;
    int d = t & 63, sub = t >> 6;
    float s = 0.f;
    size_t base = (size_t)bh * BHSTR + (size_t)(part * 256) * 64 + d;
    for (int i = 0; i < 64; i++) s += g_Kn[base + (size_t)(sub + i*4) * 64];
    __shared__ float red[256];
    red[t] = s;
    __syncthreads();
    if (t < 64) {
        float tot = red[t] + red[t+64] + red[t+128] + red[t+192];
        atomicAdd(&g_ksum[bh*64 + d], tot);
    }
}

// ---------------- knorm: Kn /= (ksum+eps) in place, emit bf16 copy ----------------
__global__ void knorm_kernel() {
    int gid = blockIdx.x * 256 + threadIdx.x;     // 4 elems each, 2048 blocks
    int i0 = gid * 4;
    int bh = i0 >> 17, d0 = i0 & 63;
    F4 v; v.v = *(const f32x4*)&g_Kn[i0];
    F4 o;
    unsigned short b[4];
#pragma unroll
    for (int j = 0; j < 4; j++) {
        float r = v.f[j] / (g_ksum[bh*64 + d0 + j] + EPSF);
        o.f[j] = r;
        b[j] = f2bf(r);
    }
    *(f32x4*)&g_Kn[i0] = o.v;
    unsigned long long packed = (unsigned long long)b[0] | ((unsigned long long)b[1] << 16)
                              | ((unsigned long long)b[2] << 32) | ((unsigned long long)b[3] << 48);
    *(unsigned long long*)&g_Kbf[i0] = packed;
}

// ---------------- attention: attn[n,m] = qinv[n] * sum_d Q[n,d]*Kn[m,d], bf16 MFMA ----------------
// grid (16,16,BH): 128x128 tile per block, 256 threads (4 waves, each 64x64)
__global__ __launch_bounds__(256) void attn_kernel(float* __restrict__ dout) {
    __shared__ short Qs[128*72], Ks[128*72];      // stride 72 shorts = 144 B
    int bh = blockIdx.z;
    int m0 = blockIdx.x * 128, n0 = blockIdx.y * 128;
    int t = threadIdx.x, lane = t & 63, w = t >> 6;
    int l15 = lane & 15, quad = lane >> 4;

    // stage: 128 rows x 64 bf16 each for Q and K
    int r = t >> 1, c0 = (t & 1) * 32;
    const short* qg = (const short*)g_Qbf + (size_t)bh * BHSTR + (size_t)(m0 + r) * 64 + c0;
    const short* kg = (const short*)g_Kbf + (size_t)bh * BHSTR + (size_t)(n0 + r) * 64 + c0;
#pragma unroll
    for (int i = 0; i < 4; i++) {
        *(short8*)&Qs[r*72 + c0 + 8*i] = *(const short8*)(qg + 8*i);
        *(short8*)&Ks[r*72 + c0 + 8*i] = *(const short8*)(kg + 8*i);
    }
    __syncthreads();

    int wm = (w >> 1) * 64, wn = (w & 1) * 64;
    f32x4 acc[4][4];
    f32x4 z4 = {0.f, 0.f, 0.f, 0.f};
#pragma unroll
    for (int i = 0; i < 4; i++)
#pragma unroll
        for (int j = 0; j < 4; j++) acc[i][j] = z4;

#pragma unroll
    for (int kk = 0; kk < 64; kk += 32) {
        short8 qa[4], kb[4];
#pragma unroll
        for (int i = 0; i < 4; i++) qa[i] = *(const short8*)&Qs[(wm + i*16 + l15)*72 + kk + quad*8];
#pragma unroll
        for (int j = 0; j < 4; j++) kb[j] = *(const short8*)&Ks[(wn + j*16 + l15)*72 + kk + quad*8];
#pragma unroll
        for (int i = 0; i < 4; i++)
#pragma unroll
            for (int j = 0; j < 4; j++) acc[i][j] = mfma_bf16(qa[i], kb[j], acc[i][j]);
    }

    float* outp = dout + OUT0 + (size_t)bh * NSEQ * NSEQ;
#pragma unroll
    for (int i = 0; i < 4; i++) {
#pragma unroll
        for (int r2 = 0; r2 < 4; r2++) {
            int row = m0 + wm + i*16 + quad*4 + r2;
            float qiv = g_qinv[bh*NSEQ + row];
#pragma unroll
            for (int j = 0; j < 4; j++) {
                int col = n0 + wn + j*16 + l15;
                F4 v; v.v = acc[i][j];
                outp[(size_t)row * NSEQ + col] = v.f[r2] * qiv;
            }
        }
    }
}

// ---------------- KV[e,d] = sum_m Kn[m,e]*V[m,d], fp32, atomic partials over m ----------------
// grid 256 = (bh, 16 parts of 128 rows), block 256
__global__ __launch_bounds__(256) void kv_kernel() {
    __shared__ float Ks2[64*64], Vs[64*64];
    int bh = blockIdx.x >> 4, part = blockIdx.x & 15;
    int t = threadIdx.x, d = t & 63, e0 = (t >> 6) * 16;
    float accv[16];
#pragma unroll
    for (int i = 0; i < 16; i++) accv[i] = 0.f;
    int sr = t >> 2, sc = (t & 3) * 16;
    for (int c = 0; c < 2; c++) {
        int nbase = part * 128 + c * 64;
        const float* kgp = g_Kn + (size_t)bh * BHSTR + (size_t)(nbase + sr) * 64 + sc;
        const float* vgp = g_Vh + (size_t)bh * BHSTR + (size_t)(nbase + sr) * 64 + sc;
#pragma unroll
        for (int i = 0; i < 4; i++) {
            *(f32x4*)&Ks2[sr*64 + sc + 4*i] = *(const f32x4*)(kgp + 4*i);
            *(f32x4*)&Vs[sr*64 + sc + 4*i]  = *(const f32x4*)(vgp + 4*i);
        }
        __syncthreads();
#pragma unroll 4
        for (int m = 0; m < 64; m++) {
            float v = Vs[m*64 + d];
            const f32x4* kr = (const f32x4*)&Ks2[m*64 + e0];
            F4 k0, k1, k2, k3;
            k0.v = kr[0]; k1.v = kr[1]; k2.v = kr[2]; k3.v = kr[3];
#pragma unroll
            for (int i = 0; i < 4; i++) accv[i]      += k0.f[i] * v;
#pragma unroll
            for (int i = 0; i < 4; i++) accv[4 + i]  += k1.f[i] * v;
#pragma unroll
            for (int i = 0; i < 4; i++) accv[8 + i]  += k2.f[i] * v;
#pragma unroll
            for (int i = 0; i < 4; i++) accv[12 + i] += k3.f[i] * v;
        }
        __syncthreads();
    }
#pragma unroll
    for (int i = 0; i < 16; i++)
        atomicAdd(&g_KV[bh*4096 + (e0 + i)*64 + d], accv[i]);
}

// ---------------- out-heads: OH[b,n,h*64+d] = qinv[n] * sum_e Qp[n,e]*KV[e,d] ----------------
// grid (16 row-blocks, BH), block 256
__global__ __launch_bounds__(256) void oh_kernel() {
    __shared__ float Qs2[128*64];   // 32 KB
    __shared__ float KVs[64*64];    // 16 KB
    int bh = blockIdx.y, r0 = blockIdx.x * 128;
    int t = threadIdx.x, d = t & 63, w = t >> 6;
    {
        int r = t >> 2, c = (t & 3) * 16;
        const float* s = g_KV + bh*4096 + r*64 + c;
#pragma unroll
        for (int i = 0; i < 4; i++) *(f32x4*)&KVs[r*64 + c + 4*i] = *(const f32x4*)(s + 4*i);
    }
    {
        int r = t >> 1, c = (t & 1) * 32;
        const float* s = g_Qp + (size_t)bh * BHSTR + (size_t)(r0 + r) * 64 + c;
#pragma unroll
        for (int i = 0; i < 8; i++) *(f32x4*)&Qs2[r*64 + c + 4*i] = *(const f32x4*)(s + 4*i);
    }
    __syncthreads();
    float kvc[64];
#pragma unroll
    for (int e = 0; e < 64; e++) kvc[e] = KVs[e*64 + d];
    int b = bh >> 3, h = bh & 7;
    for (int rr = 0; rr < 32; rr++) {
        int row = w * 32 + rr;
        const f32x4* qr = (const f32x4*)&Qs2[row*64];
        float a = 0.f;
#pragma unroll
        for (int e4 = 0; e4 < 16; e4++) {
            F4 q; q.v = qr[e4];
            a += q.f[0]*kvc[4*e4] + q.f[1]*kvc[4*e4+1] + q.f[2]*kvc[4*e4+2] + q.f[3]*kvc[4*e4+3];
        }
        int grow = r0 + row;
        float val = a * g_qinv[bh*NSEQ + grow];
        g_OH[((size_t)b*NSEQ + grow)*512 + h*64 + d] = val;
    }
}

// ---------------- launch ----------------
extern "C" void kernel_launch(void* const* d_in, const int* in_sizes, int n_in,
                              void* d_out, int out_size, void* d_ws, size_t ws_size,
                              hipStream_t stream) {
    const float* q  = (const float*)d_in[0];
    const float* k  = (const float*)d_in[1];
    const float* v  = (const float*)d_in[2];
    const float* Wq = (const float*)d_in[3];
    const float* bq = (const float*)d_in[4];
    const float* Wk = (const float*)d_in[5];
    const float* bk = (const float*)d_in[6];
    const float* Wv = (const float*)d_in[7];
    const float* bv = (const float*)d_in[8];
    const float* Wo = (const float*)d_in[9];
    const float* bo = (const float*)d_in[10];
    float* out = (float*)d_out;

    zero_small<<<256, 256, 0, stream>>>();

    dim3 gproj(32, 8);
    gemm_split<<<gproj, 256, 0, stream>>>(q, Wq, bq, out, 0);
    gemm_split<<<gproj, 256, 0, stream>>>(k, Wk, bk, out, 1);
    gemm_split<<<gproj, 256, 0, stream>>>(v, Wv, bv, out, 2);

    qsum_kernel<<<8192, 256, 0, stream>>>();
    ksum_kernel<<<128, 256, 0, stream>>>();
    knorm_kernel<<<2048, 256, 0, stream>>>();

    attn_kernel<<<dim3(16, 16, BH), 256, 0, stream>>>(out);

    kv_kernel<<<256, 256, 0, stream>>>();
    oh_kernel<<<dim3(16, BH), 256, 0, stream>>>();

    gemm_split<<<gproj, 256, 0, stream>>>(nullptr, Wo, bo, out, 3);
}

// Round 2
// 405.108 us; speedup vs baseline: 1.1638x; 1.1638x over previous
//
#include <hip/hip_runtime.h>
#include <math.h>

// ---------------- problem constants ----------------
#define NSEQ  2048
#define DM    512
#define NH    8
#define DK    64
#define MROWS 4096             // B*N = 2*2048
#define BH    16               // B*H
#define BHSTR (NSEQ*DK)        // 131072 elems per (b,h) slab
#define SLAB  (BH*BHSTR)       // 2,097,152
#define EPSF  1e-8f
#define OUT0  (MROWS*DM)       // start of attention region in d_out

typedef __attribute__((ext_vector_type(8))) short short8;
typedef __attribute__((ext_vector_type(4))) float f32x4;
union S8 { short8 v; short s[8]; };
union F4 { f32x4 v; float f[4]; };

// ---------------- static device scratch ----------------
// split-bf16 inputs (hi+lo for q,k,Wq,Wk; hi only for v,Wv,Wo)
__device__ short g_qh[MROWS*DM], g_ql[MROWS*DM];
__device__ short g_kh[MROWS*DM], g_kl[MROWS*DM];
__device__ short g_vh[MROWS*DM];
__device__ short g_wqh[DM*DM], g_wql[DM*DM];
__device__ short g_wkh[DM*DM], g_wkl[DM*DM];
__device__ short g_wvh[DM*DM], g_woh[DM*DM];
// intermediates
__device__ unsigned short g_Qbf[SLAB];   // bf16( (elu(Q)+1) / (ksum+eps) )  [bh][n][d]
__device__ unsigned short g_Kbf[SLAB];   // bf16( elu(K)+1 )                 [bh][n][d]
__device__ float          g_Vf[SLAB];    // fp32 V heads                     [bh][n][d]
__device__ short          g_OHbf[MROWS*DM]; // bf16 out-heads [b][n][h*64+d]
__device__ float          g_qinv[BH*NSEQ];
__device__ float          g_ksum[BH*DK];
__device__ float          g_KV[BH*DK*DK];

// ---------------- helpers ----------------
__device__ __forceinline__ unsigned short f2bf(float x) {
    union { float f; unsigned u; } v; v.f = x;
    unsigned r = v.u + 0x7fffu + ((v.u >> 16) & 1u);
    return (unsigned short)(r >> 16);
}
__device__ __forceinline__ float bf2f(unsigned short h) {
    union { unsigned u; float f; } v; v.u = ((unsigned)h) << 16; return v.f;
}
__device__ __forceinline__ f32x4 mfma_bf16(short8 a, short8 b, f32x4 c) {
    return __builtin_amdgcn_mfma_f32_16x16x32_bf16(a, b, c, 0, 0, 0);
}
__device__ __forceinline__ float elu1(float x) {
    return (x > 0.f) ? (x + 1.f) : __expf(x);
}
// async global->LDS, 16B per lane; LDS dst = wave-uniform base + lane*16
__device__ __forceinline__ void gl_lds16(const void* gsrc, void* ldst) {
    __builtin_amdgcn_global_load_lds(
        (__attribute__((address_space(1))) void*)(unsigned long long)(gsrc),
        (__attribute__((address_space(3))) void*)(unsigned)(unsigned long long)(ldst),
        16, 0, 0);
}

// ---------------- prep: fp32 -> split/plain bf16, zero accumulators ----------------
__global__ __launch_bounds__(256) void prep_kernel(const float* __restrict__ q, const float* __restrict__ k,
                                                   const float* __restrict__ v, const float* __restrict__ wq,
                                                   const float* __restrict__ wk, const float* __restrict__ wv,
                                                   const float* __restrict__ wo) {
    int b = blockIdx.x, t = threadIdx.x;
    if (b < 33) {                       // zero g_KV (65536) + g_ksum (1024)
        int z = b * 2048 + t * 8;
#pragma unroll
        for (int i = 0; i < 8; i++) {
            int zz = z + i;
            if (zz < 65536) g_KV[zz] = 0.f;
            else if (zz < 66560) g_ksum[zz - 65536] = 0.f;
        }
    }
    const float* src; short* hi; short* lo; int off; int split;
    if (b < 1024)      { src = q;  hi = g_qh;  lo = g_ql;  off = b * 2048;          split = 1; }
    else if (b < 2048) { src = k;  hi = g_kh;  lo = g_kl;  off = (b-1024) * 2048;   split = 1; }
    else if (b < 3072) { src = v;  hi = g_vh;  lo = g_vh;  off = (b-2048) * 2048;   split = 0; }
    else if (b < 3200) { src = wq; hi = g_wqh; lo = g_wql; off = (b-3072) * 2048;   split = 1; }
    else if (b < 3328) { src = wk; hi = g_wkh; lo = g_wkl; off = (b-3200) * 2048;   split = 1; }
    else if (b < 3456) { src = wv; hi = g_wvh; lo = g_wvh; off = (b-3328) * 2048;   split = 0; }
    else               { src = wo; hi = g_woh; lo = g_woh; off = (b-3456) * 2048;   split = 0; }
    int idx = off + t * 8;
    F4 a0, a1; a0.v = *(const f32x4*)(src + idx); a1.v = *(const f32x4*)(src + idx + 4);
    S8 h, l;
#pragma unroll
    for (int i = 0; i < 4; i++) {
        unsigned short hb = f2bf(a0.f[i]); h.s[i] = (short)hb;
        l.s[i] = (short)f2bf(a0.f[i] - bf2f(hb));
    }
#pragma unroll
    for (int i = 0; i < 4; i++) {
        unsigned short hb = f2bf(a1.f[i]); h.s[4+i] = (short)hb;
        l.s[4+i] = (short)f2bf(a1.f[i] - bf2f(hb));
    }
    *(short8*)(hi + idx) = h.v;
    if (split) *(short8*)(lo + idx) = l.v;
}

// ---------------- unified MFMA GEMM: C[m,n] = sum_k A[m,k]*W[n,k] + bias[n] ----------------
// M=4096, N=512, K=512. Tile 128x64, BK=64, grid (32,8), 256 threads (4 waves).
// SPLIT=1: acc += Ah*Bh + Ah*Bl + Al*Bh (fp32-class precision).
// Staging: global_load_lds dwordx4 with XOR-swizzled source granules:
//   LDS[r][p] (16B granules, 8/row) = global[r][p ^ (r&7)]  -> conflict-free frag reads.
// mode 0: Q proj -> Qbf=(elu+1)/ksd, qinv (in-epilogue rowsum)    [needs ksum done]
// mode 1: K proj -> Kbf=elu+1, ksum column-sum atomics
// mode 2: V proj -> g_Vf fp32
// mode 3: A=g_OHbf -> dout = OH@Wo^T + bo
template<int SPLIT>
__global__ __launch_bounds__(256) void gemm_bf16(const float* __restrict__ bias,
                                                 float* __restrict__ dout, int mode) {
    __shared__ short sAh[128*64];
    __shared__ short sBh[64*64];
    __shared__ short sAl[SPLIT ? 128*64 : 8];
    __shared__ short sBl[SPLIT ? 64*64 : 8];

    const short *Ahi, *Alo = nullptr, *Bhi, *Blo = nullptr;
    if (mode == 0)      { Ahi = g_qh;   Alo = g_ql;  Bhi = g_wqh; Blo = g_wql; }
    else if (mode == 1) { Ahi = g_kh;   Alo = g_kl;  Bhi = g_wkh; Blo = g_wkl; }
    else if (mode == 2) { Ahi = g_vh;   Bhi = g_wvh; }
    else                { Ahi = g_OHbf; Bhi = g_woh; }

    int t = threadIdx.x, lane = t & 63, w = t >> 6;
    int l15 = lane & 15, quad = lane >> 4;
    int m0 = blockIdx.x * 128, n0 = blockIdx.y * 64;
    int r_in = lane >> 3, gq = lane & 7;
    int scol = (gq ^ r_in) << 3;          // swizzled source col (shorts)

    f32x4 acc[2][4];
    f32x4 z4 = {0.f, 0.f, 0.f, 0.f};
#pragma unroll
    for (int i = 0; i < 2; i++)
#pragma unroll
        for (int j = 0; j < 4; j++) acc[i][j] = z4;

    for (int k0 = 0; k0 < 512; k0 += 64) {
#pragma unroll
        for (int ii = 0; ii < 4; ii++) {          // A: 16 DMA insts, 4/wave
            int i = w * 4 + ii;
            size_t so = (size_t)(m0 + i*8 + r_in) * 512 + k0 + scol;
            gl_lds16(Ahi + so, &sAh[i * 512]);
            if (SPLIT) gl_lds16(Alo + so, &sAl[i * 512]);
        }
#pragma unroll
        for (int ii = 0; ii < 2; ii++) {          // B: 8 DMA insts, 2/wave
            int i = w * 2 + ii;
            size_t so = (size_t)(n0 + i*8 + r_in) * 512 + k0 + scol;
            gl_lds16(Bhi + so, &sBh[i * 512]);
            if (SPLIT) gl_lds16(Blo + so, &sBl[i * 512]);
        }
        __syncthreads();                          // drains vmcnt(0): DMA complete

#pragma unroll
        for (int ks = 0; ks < 2; ks++) {
            int kg = ks * 4 + quad;
            int sw = (kg ^ (l15 & 7)) << 3;
            short8 ah[2], al[2], bh[4], bl[4];
#pragma unroll
            for (int i = 0; i < 2; i++) {
                int ad = (w*32 + i*16 + l15) * 64 + sw;
                ah[i] = *(const short8*)&sAh[ad];
                if (SPLIT) al[i] = *(const short8*)&sAl[ad];
            }
#pragma unroll
            for (int j = 0; j < 4; j++) {
                int ad = (j*16 + l15) * 64 + sw;
                bh[j] = *(const short8*)&sBh[ad];
                if (SPLIT) bl[j] = *(const short8*)&sBl[ad];
            }
#pragma unroll
            for (int i = 0; i < 2; i++)
#pragma unroll
                for (int j = 0; j < 4; j++) {
                    acc[i][j] = mfma_bf16(ah[i], bh[j], acc[i][j]);
                    if (SPLIT) {
                        acc[i][j] = mfma_bf16(ah[i], bl[j], acc[i][j]);
                        acc[i][j] = mfma_bf16(al[i], bh[j], acc[i][j]);
                    }
                }
        }
        __syncthreads();
    }

    // ---- epilogue ----
    int head = blockIdx.y;
    int bh16 = ((m0 >> 11) << 3) + head;          // (b*8 + h), valid for modes 0..2
    if (mode == 3) {
#pragma unroll
        for (int j = 0; j < 4; j++) {
            int col = n0 + j*16 + l15;
            float bsv = bias[col];
#pragma unroll
            for (int i = 0; i < 2; i++) {
                F4 v; v.v = acc[i][j];
#pragma unroll
                for (int r = 0; r < 4; r++) {
                    int row = m0 + w*32 + i*16 + quad*4 + r;
                    dout[(size_t)row * 512 + col] = v.f[r] + bsv;
                }
            }
        }
    } else if (mode == 2) {
#pragma unroll
        for (int j = 0; j < 4; j++) {
            int col = n0 + j*16 + l15;
            float bsv = bias[col];
            int dd = col & 63;
#pragma unroll
            for (int i = 0; i < 2; i++) {
                F4 v; v.v = acc[i][j];
#pragma unroll
                for (int r = 0; r < 4; r++) {
                    int nn = (m0 + w*32 + i*16 + quad*4 + r) & 2047;
                    g_Vf[(size_t)bh16 * BHSTR + nn*64 + dd] = v.f[r] + bsv;
                }
            }
        }
    } else {
        float e[2][4][4];
#pragma unroll
        for (int j = 0; j < 4; j++) {
            float bsv = bias[n0 + j*16 + l15];
#pragma unroll
            for (int i = 0; i < 2; i++) {
                F4 v; v.v = acc[i][j];
#pragma unroll
                for (int r = 0; r < 4; r++) e[i][j][r] = elu1(v.f[r] + bsv);
            }
        }
        if (mode == 0) {
            float rks[4];
#pragma unroll
            for (int j = 0; j < 4; j++)
                rks[j] = 1.f / (g_ksum[bh16*64 + j*16 + l15] + EPSF);
#pragma unroll
            for (int i = 0; i < 2; i++) {
#pragma unroll
                for (int r = 0; r < 4; r++) {
                    float s = e[i][0][r] + e[i][1][r] + e[i][2][r] + e[i][3][r];
                    s += __shfl_xor(s, 1); s += __shfl_xor(s, 2);
                    s += __shfl_xor(s, 4); s += __shfl_xor(s, 8);
                    if (l15 == 0) {
                        int nn = (m0 + w*32 + i*16 + quad*4 + r) & 2047;
                        g_qinv[bh16*NSEQ + nn] = 1.f / (s + EPSF);
                    }
                }
#pragma unroll
                for (int j = 0; j < 4; j++) {
                    int dd = j*16 + l15;
#pragma unroll
                    for (int r = 0; r < 4; r++) {
                        int nn = (m0 + w*32 + i*16 + quad*4 + r) & 2047;
                        g_Qbf[(size_t)bh16 * BHSTR + nn*64 + dd] = f2bf(e[i][j][r] * rks[j]);
                    }
                }
            }
        } else { // mode 1
#pragma unroll
            for (int j = 0; j < 4; j++) {
                int dd = j*16 + l15;
                float s = 0.f;
#pragma unroll
                for (int i = 0; i < 2; i++)
#pragma unroll
                    for (int r = 0; r < 4; r++) {
                        int nn = (m0 + w*32 + i*16 + quad*4 + r) & 2047;
                        g_Kbf[(size_t)bh16 * BHSTR + nn*64 + dd] = f2bf(e[i][j][r]);
                        s += e[i][j][r];
                    }
                s += __shfl_xor(s, 16); s += __shfl_xor(s, 32);
                if (lane < 16) atomicAdd(&g_ksum[bh16*64 + dd], s);
            }
        }
    }
}

// ---------------- attention: attn[n,m] = qinv[n]*sum_d Qbf[n,d]*Kbf[m,d] ----------------
// grid (16,16,BH), 128x128 tile, 4 waves of 64x64; global_load_lds staging, swizzled.
__global__ __launch_bounds__(256) void attn_kernel(float* __restrict__ dout) {
    __shared__ short Qs[128*64], Ks[128*64];
    int bh = blockIdx.z;
    int m0 = blockIdx.x * 128, n0 = blockIdx.y * 128;
    int t = threadIdx.x, lane = t & 63, w = t >> 6;
    int l15 = lane & 15, quad = lane >> 4;
    int r_in = lane >> 3, gq = lane & 7;
    int scol = (gq ^ r_in) << 3;

    const short* qb = (const short*)g_Qbf + (size_t)bh * BHSTR;
    const short* kb = (const short*)g_Kbf + (size_t)bh * BHSTR;
#pragma unroll
    for (int ii = 0; ii < 4; ii++) {
        int i = w * 4 + ii;
        gl_lds16(qb + (size_t)(m0 + i*8 + r_in) * 64 + scol, &Qs[i * 512]);
        gl_lds16(kb + (size_t)(n0 + i*8 + r_in) * 64 + scol, &Ks[i * 512]);
    }
    __syncthreads();

    int wm = (w >> 1) * 64, wn = (w & 1) * 64;
    f32x4 acc[4][4];
    f32x4 z4 = {0.f, 0.f, 0.f, 0.f};
#pragma unroll
    for (int i = 0; i < 4; i++)
#pragma unroll
        for (int j = 0; j < 4; j++) acc[i][j] = z4;

#pragma unroll
    for (int ks = 0; ks < 2; ks++) {
        int kg = ks * 4 + quad;
        int sw = (kg ^ (l15 & 7)) << 3;
        short8 qa[4], kbf[4];
#pragma unroll
        for (int i = 0; i < 4; i++) qa[i]  = *(const short8*)&Qs[(wm + i*16 + l15) * 64 + sw];
#pragma unroll
        for (int j = 0; j < 4; j++) kbf[j] = *(const short8*)&Ks[(wn + j*16 + l15) * 64 + sw];
#pragma unroll
        for (int i = 0; i < 4; i++)
#pragma unroll
            for (int j = 0; j < 4; j++) acc[i][j] = mfma_bf16(qa[i], kbf[j], acc[i][j]);
    }

    float* outp = dout + OUT0 + (size_t)bh * NSEQ * NSEQ;
#pragma unroll
    for (int i = 0; i < 4; i++) {
#pragma unroll
        for (int r2 = 0; r2 < 4; r2++) {
            int row = m0 + wm + i*16 + quad*4 + r2;
            float qiv = g_qinv[bh*NSEQ + row];
#pragma unroll
            for (int j = 0; j < 4; j++) {
                F4 v; v.v = acc[i][j];
                outp[(size_t)row * NSEQ + (n0 + wn + j*16 + l15)] = v.f[r2] * qiv;
            }
        }
    }
}

// ---------------- KV[e,d] = sum_m Kbf[m,e]*V[m,d] (raw K), fp32 atomic partials ----------------
__global__ __launch_bounds__(256) void kv_kernel() {
    __shared__ float Ks2[64*64], Vs[64*64];
    int bh = blockIdx.x >> 4, part = blockIdx.x & 15;
    int t = threadIdx.x, d = t & 63, e0 = (t >> 6) * 16;
    float accv[16];
#pragma unroll
    for (int i = 0; i < 16; i++) accv[i] = 0.f;
    int sr = t >> 2, sc = (t & 3) * 16;
    for (int c = 0; c < 2; c++) {
        int nbase = part * 128 + c * 64;
        const unsigned short* kgp = g_Qbf, *dummy = kgp; (void)dummy;
        kgp = g_Kbf + (size_t)bh * BHSTR + (size_t)(nbase + sr) * 64 + sc;
        const float* vgp = g_Vf + (size_t)bh * BHSTR + (size_t)(nbase + sr) * 64 + sc;
        S8 k0, k1;
        k0.v = *(const short8*)(kgp);
        k1.v = *(const short8*)(kgp + 8);
#pragma unroll
        for (int i = 0; i < 8; i++) Ks2[sr*64 + sc + i]     = bf2f((unsigned short)k0.s[i]);
#pragma unroll
        for (int i = 0; i < 8; i++) Ks2[sr*64 + sc + 8 + i] = bf2f((unsigned short)k1.s[i]);
#pragma unroll
        for (int i = 0; i < 4; i++) *(f32x4*)&Vs[sr*64 + sc + 4*i] = *(const f32x4*)(vgp + 4*i);
        __syncthreads();
#pragma unroll 4
        for (int m = 0; m < 64; m++) {
            float v = Vs[m*64 + d];
            const f32x4* kr = (const f32x4*)&Ks2[m*64 + e0];
            F4 q0, q1, q2, q3;
            q0.v = kr[0]; q1.v = kr[1]; q2.v = kr[2]; q3.v = kr[3];
#pragma unroll
            for (int i = 0; i < 4; i++) accv[i]      += q0.f[i] * v;
#pragma unroll
            for (int i = 0; i < 4; i++) accv[4 + i]  += q1.f[i] * v;
#pragma unroll
            for (int i = 0; i < 4; i++) accv[8 + i]  += q2.f[i] * v;
#pragma unroll
            for (int i = 0; i < 4; i++) accv[12 + i] += q3.f[i] * v;
        }
        __syncthreads();
    }
#pragma unroll
    for (int i = 0; i < 16; i++)
        atomicAdd(&g_KV[bh*4096 + (e0 + i)*64 + d], accv[i]);
}

// ---------------- out-heads: OHbf[b,n,h*64+d] = bf16( qinv[n]*sum_e Qbf[n,e]*KV[e,d] ) ----------------
__global__ __launch_bounds__(256) void oh_kernel() {
    __shared__ float Qs2[128*64];
    __shared__ float KVs[64*64];
    int bh = blockIdx.y, r0 = blockIdx.x * 128;
    int t = threadIdx.x, d = t & 63, w = t >> 6;
    {
        int r = t >> 2, c = (t & 3) * 16;
        const float* s = g_KV + bh*4096 + r*64 + c;
#pragma unroll
        for (int i = 0; i < 4; i++) *(f32x4*)&KVs[r*64 + c + 4*i] = *(const f32x4*)(s + 4*i);
    }
    {
        int r = t >> 1, c = (t & 1) * 32;
        const unsigned short* s = g_Qbf + (size_t)bh * BHSTR + (size_t)(r0 + r) * 64 + c;
#pragma unroll
        for (int i = 0; i < 4; i++) {
            S8 x; x.v = *(const short8*)(s + 8*i);
#pragma unroll
            for (int j = 0; j < 8; j++) Qs2[r*64 + c + 8*i + j] = bf2f((unsigned short)x.s[j]);
        }
    }
    __syncthreads();
    float kvc[64];
#pragma unroll
    for (int e = 0; e < 64; e++) kvc[e] = KVs[e*64 + d];
    int b = bh >> 3, h = bh & 7;
    for (int rr = 0; rr < 32; rr++) {
        int row = w * 32 + rr;
        const f32x4* qr = (const f32x4*)&Qs2[row*64];
        float a = 0.f;
#pragma unroll
        for (int e4 = 0; e4 < 16; e4++) {
            F4 q; q.v = qr[e4];
            a += q.f[0]*kvc[4*e4] + q.f[1]*kvc[4*e4+1] + q.f[2]*kvc[4*e4+2] + q.f[3]*kvc[4*e4+3];
        }
        int grow = r0 + row;
        float val = a * g_qinv[bh*NSEQ + grow];
        g_OHbf[((size_t)b*NSEQ + grow)*512 + h*64 + d] = (short)f2bf(val);
    }
}

// ---------------- launch ----------------
extern "C" void kernel_launch(void* const* d_in, const int* in_sizes, int n_in,
                              void* d_out, int out_size, void* d_ws, size_t ws_size,
                              hipStream_t stream) {
    const float* q  = (const float*)d_in[0];
    const float* k  = (const float*)d_in[1];
    const float* v  = (const float*)d_in[2];
    const float* Wq = (const float*)d_in[3];
    const float* bq = (const float*)d_in[4];
    const float* Wk = (const float*)d_in[5];
    const float* bk = (const float*)d_in[6];
    const float* Wv = (const float*)d_in[7];
    const float* bv = (const float*)d_in[8];
    const float* Wo = (const float*)d_in[9];
    const float* bo = (const float*)d_in[10];
    float* out = (float*)d_out;

    prep_kernel<<<3584, 256, 0, stream>>>(q, k, v, Wq, Wk, Wv, Wo);

    dim3 gproj(32, 8);
    gemm_bf16<1><<<gproj, 256, 0, stream>>>(bk, nullptr, 1);   // K first (produces ksum)
    gemm_bf16<1><<<gproj, 256, 0, stream>>>(bq, nullptr, 0);   // Q (consumes ksum)
    gemm_bf16<0><<<gproj, 256, 0, stream>>>(bv, nullptr, 2);   // V

    attn_kernel<<<dim3(16, 16, BH), 256, 0, stream>>>(out);

    kv_kernel<<<256, 256, 0, stream>>>();
    oh_kernel<<<dim3(16, BH), 256, 0, stream>>>();

    gemm_bf16<0><<<gproj, 256, 0, stream>>>(bo, out, 3);       // final projection
}

// Round 3
// 393.503 us; speedup vs baseline: 1.1981x; 1.0295x over previous
//
#include <hip/hip_runtime.h>
#include <math.h>

// ---------------- problem constants ----------------
#define NSEQ  2048
#define DM    512
#define NH    8
#define DK    64
#define MROWS 4096             // B*N = 2*2048
#define BH    16               // B*H
#define BHSTR (NSEQ*DK)        // 131072 elems per (b,h) slab
#define SLAB  (BH*BHSTR)       // 2,097,152
#define EPSF  1e-8f
#define OUT0  (MROWS*DM)       // start of attention region in d_out

typedef __attribute__((ext_vector_type(8))) short short8;
typedef __attribute__((ext_vector_type(4))) float f32x4;
union S8 { short8 v; short s[8]; };
union F4 { f32x4 v; float f[4]; };

// ---------------- static device scratch ----------------
__device__ short g_qh[MROWS*DM], g_ql[MROWS*DM];
__device__ short g_kh[MROWS*DM], g_kl[MROWS*DM];
__device__ short g_vh[MROWS*DM];
__device__ short g_wqh[DM*DM], g_wql[DM*DM];
__device__ short g_wkh[DM*DM], g_wkl[DM*DM];
__device__ short g_wvh[DM*DM], g_woh[DM*DM];
__device__ unsigned short g_Qbf[SLAB];   // bf16( (elu(Q)+1) / (ksum+eps) )  [bh][n][d]
__device__ unsigned short g_Kbf[SLAB];   // bf16( elu(K)+1 )                 [bh][n][d]
__device__ float          g_Vf[SLAB];    // fp32 V heads                     [bh][n][d]
__device__ short          g_OHbf[MROWS*DM]; // bf16 out-heads [b][n][h*64+d]
__device__ float          g_qinv[BH*NSEQ];
__device__ float          g_ksum[BH*DK];
__device__ float          g_KV[BH*DK*DK];

// ---------------- helpers ----------------
__device__ __forceinline__ unsigned short f2bf(float x) {
    union { float f; unsigned u; } v; v.f = x;
    unsigned r = v.u + 0x7fffu + ((v.u >> 16) & 1u);
    return (unsigned short)(r >> 16);
}
__device__ __forceinline__ float bf2f(unsigned short h) {
    union { unsigned u; float f; } v; v.u = ((unsigned)h) << 16; return v.f;
}
__device__ __forceinline__ f32x4 mfma_bf16(short8 a, short8 b, f32x4 c) {
    return __builtin_amdgcn_mfma_f32_16x16x32_bf16(a, b, c, 0, 0, 0);
}
__device__ __forceinline__ float elu1(float x) {
    return (x > 0.f) ? (x + 1.f) : __expf(x);
}
__device__ __forceinline__ void gl_lds16(const void* gsrc, void* ldst) {
    __builtin_amdgcn_global_load_lds(
        (__attribute__((address_space(1))) void*)(unsigned long long)(gsrc),
        (__attribute__((address_space(3))) void*)(unsigned)(unsigned long long)(ldst),
        16, 0, 0);
}

// ---------------- prep: fp32 -> split/plain bf16, zero accumulators ----------------
__global__ __launch_bounds__(256) void prep_kernel(const float* __restrict__ q, const float* __restrict__ k,
                                                   const float* __restrict__ v, const float* __restrict__ wq,
                                                   const float* __restrict__ wk, const float* __restrict__ wv,
                                                   const float* __restrict__ wo) {
    int b = blockIdx.x, t = threadIdx.x;
    if (b < 33) {                       // zero g_KV (65536) + g_ksum (1024)
        int z = b * 2048 + t * 8;
#pragma unroll
        for (int i = 0; i < 8; i++) {
            int zz = z + i;
            if (zz < 65536) g_KV[zz] = 0.f;
            else if (zz < 66560) g_ksum[zz - 65536] = 0.f;
        }
    }
    const float* src; short* hi; short* lo; int off; int split;
    if (b < 1024)      { src = q;  hi = g_qh;  lo = g_ql;  off = b * 2048;          split = 1; }
    else if (b < 2048) { src = k;  hi = g_kh;  lo = g_kl;  off = (b-1024) * 2048;   split = 1; }
    else if (b < 3072) { src = v;  hi = g_vh;  lo = g_vh;  off = (b-2048) * 2048;   split = 0; }
    else if (b < 3200) { src = wq; hi = g_wqh; lo = g_wql; off = (b-3072) * 2048;   split = 1; }
    else if (b < 3328) { src = wk; hi = g_wkh; lo = g_wkl; off = (b-3200) * 2048;   split = 1; }
    else if (b < 3456) { src = wv; hi = g_wvh; lo = g_wvh; off = (b-3328) * 2048;   split = 0; }
    else               { src = wo; hi = g_woh; lo = g_woh; off = (b-3456) * 2048;   split = 0; }
    int idx = off + t * 8;
    F4 a0, a1; a0.v = *(const f32x4*)(src + idx); a1.v = *(const f32x4*)(src + idx + 4);
    S8 h, l;
#pragma unroll
    for (int i = 0; i < 4; i++) {
        unsigned short hb = f2bf(a0.f[i]); h.s[i] = (short)hb;
        l.s[i] = (short)f2bf(a0.f[i] - bf2f(hb));
    }
#pragma unroll
    for (int i = 0; i < 4; i++) {
        unsigned short hb = f2bf(a1.f[i]); h.s[4+i] = (short)hb;
        l.s[4+i] = (short)f2bf(a1.f[i] - bf2f(hb));
    }
    *(short8*)(hi + idx) = h.v;
    if (split) *(short8*)(lo + idx) = l.v;
}

// ---------------- unified MFMA GEMM (unchanged from R2) ----------------
template<int SPLIT>
__global__ __launch_bounds__(256) void gemm_bf16(const float* __restrict__ bias,
                                                 float* __restrict__ dout, int mode) {
    __shared__ short sAh[128*64];
    __shared__ short sBh[64*64];
    __shared__ short sAl[SPLIT ? 128*64 : 8];
    __shared__ short sBl[SPLIT ? 64*64 : 8];

    const short *Ahi, *Alo = nullptr, *Bhi, *Blo = nullptr;
    if (mode == 0)      { Ahi = g_qh;   Alo = g_ql;  Bhi = g_wqh; Blo = g_wql; }
    else if (mode == 1) { Ahi = g_kh;   Alo = g_kl;  Bhi = g_wkh; Blo = g_wkl; }
    else if (mode == 2) { Ahi = g_vh;   Bhi = g_wvh; }
    else                { Ahi = g_OHbf; Bhi = g_woh; }

    int t = threadIdx.x, lane = t & 63, w = t >> 6;
    int l15 = lane & 15, quad = lane >> 4;
    int m0 = blockIdx.x * 128, n0 = blockIdx.y * 64;
    int r_in = lane >> 3, gq = lane & 7;
    int scol = (gq ^ r_in) << 3;

    f32x4 acc[2][4];
    f32x4 z4 = {0.f, 0.f, 0.f, 0.f};
#pragma unroll
    for (int i = 0; i < 2; i++)
#pragma unroll
        for (int j = 0; j < 4; j++) acc[i][j] = z4;

    for (int k0 = 0; k0 < 512; k0 += 64) {
#pragma unroll
        for (int ii = 0; ii < 4; ii++) {
            int i = w * 4 + ii;
            size_t so = (size_t)(m0 + i*8 + r_in) * 512 + k0 + scol;
            gl_lds16(Ahi + so, &sAh[i * 512]);
            if (SPLIT) gl_lds16(Alo + so, &sAl[i * 512]);
        }
#pragma unroll
        for (int ii = 0; ii < 2; ii++) {
            int i = w * 2 + ii;
            size_t so = (size_t)(n0 + i*8 + r_in) * 512 + k0 + scol;
            gl_lds16(Bhi + so, &sBh[i * 512]);
            if (SPLIT) gl_lds16(Blo + so, &sBl[i * 512]);
        }
        __syncthreads();

#pragma unroll
        for (int ks = 0; ks < 2; ks++) {
            int kg = ks * 4 + quad;
            int sw = (kg ^ (l15 & 7)) << 3;
            short8 ah[2], al[2], bh[4], bl[4];
#pragma unroll
            for (int i = 0; i < 2; i++) {
                int ad = (w*32 + i*16 + l15) * 64 + sw;
                ah[i] = *(const short8*)&sAh[ad];
                if (SPLIT) al[i] = *(const short8*)&sAl[ad];
            }
#pragma unroll
            for (int j = 0; j < 4; j++) {
                int ad = (j*16 + l15) * 64 + sw;
                bh[j] = *(const short8*)&sBh[ad];
                if (SPLIT) bl[j] = *(const short8*)&sBl[ad];
            }
#pragma unroll
            for (int i = 0; i < 2; i++)
#pragma unroll
                for (int j = 0; j < 4; j++) {
                    acc[i][j] = mfma_bf16(ah[i], bh[j], acc[i][j]);
                    if (SPLIT) {
                        acc[i][j] = mfma_bf16(ah[i], bl[j], acc[i][j]);
                        acc[i][j] = mfma_bf16(al[i], bh[j], acc[i][j]);
                    }
                }
        }
        __syncthreads();
    }

    int head = blockIdx.y;
    int bh16 = ((m0 >> 11) << 3) + head;
    if (mode == 3) {
#pragma unroll
        for (int j = 0; j < 4; j++) {
            int col = n0 + j*16 + l15;
            float bsv = bias[col];
#pragma unroll
            for (int i = 0; i < 2; i++) {
                F4 v; v.v = acc[i][j];
#pragma unroll
                for (int r = 0; r < 4; r++) {
                    int row = m0 + w*32 + i*16 + quad*4 + r;
                    dout[(size_t)row * 512 + col] = v.f[r] + bsv;
                }
            }
        }
    } else if (mode == 2) {
#pragma unroll
        for (int j = 0; j < 4; j++) {
            int col = n0 + j*16 + l15;
            float bsv = bias[col];
            int dd = col & 63;
#pragma unroll
            for (int i = 0; i < 2; i++) {
                F4 v; v.v = acc[i][j];
#pragma unroll
                for (int r = 0; r < 4; r++) {
                    int nn = (m0 + w*32 + i*16 + quad*4 + r) & 2047;
                    g_Vf[(size_t)bh16 * BHSTR + nn*64 + dd] = v.f[r] + bsv;
                }
            }
        }
    } else {
        float e[2][4][4];
#pragma unroll
        for (int j = 0; j < 4; j++) {
            float bsv = bias[n0 + j*16 + l15];
#pragma unroll
            for (int i = 0; i < 2; i++) {
                F4 v; v.v = acc[i][j];
#pragma unroll
                for (int r = 0; r < 4; r++) e[i][j][r] = elu1(v.f[r] + bsv);
            }
        }
        if (mode == 0) {
            float rks[4];
#pragma unroll
            for (int j = 0; j < 4; j++)
                rks[j] = 1.f / (g_ksum[bh16*64 + j*16 + l15] + EPSF);
#pragma unroll
            for (int i = 0; i < 2; i++) {
#pragma unroll
                for (int r = 0; r < 4; r++) {
                    float s = e[i][0][r] + e[i][1][r] + e[i][2][r] + e[i][3][r];
                    s += __shfl_xor(s, 1); s += __shfl_xor(s, 2);
                    s += __shfl_xor(s, 4); s += __shfl_xor(s, 8);
                    if (l15 == 0) {
                        int nn = (m0 + w*32 + i*16 + quad*4 + r) & 2047;
                        g_qinv[bh16*NSEQ + nn] = 1.f / (s + EPSF);
                    }
                }
#pragma unroll
                for (int j = 0; j < 4; j++) {
                    int dd = j*16 + l15;
#pragma unroll
                    for (int r = 0; r < 4; r++) {
                        int nn = (m0 + w*32 + i*16 + quad*4 + r) & 2047;
                        g_Qbf[(size_t)bh16 * BHSTR + nn*64 + dd] = f2bf(e[i][j][r] * rks[j]);
                    }
                }
            }
        } else { // mode 1
#pragma unroll
            for (int j = 0; j < 4; j++) {
                int dd = j*16 + l15;
                float s = 0.f;
#pragma unroll
                for (int i = 0; i < 2; i++)
#pragma unroll
                    for (int r = 0; r < 4; r++) {
                        int nn = (m0 + w*32 + i*16 + quad*4 + r) & 2047;
                        g_Kbf[(size_t)bh16 * BHSTR + nn*64 + dd] = f2bf(e[i][j][r]);
                        s += e[i][j][r];
                    }
                s += __shfl_xor(s, 16); s += __shfl_xor(s, 32);
                if (lane < 16) atomicAdd(&g_ksum[bh16*64 + dd], s);
            }
        }
    }
}

// ---------------- attention: attn[n,m] = qinv[n]*sum_d Qbf[n,d]*Kbf[m,d] ----------------
// grid (16,16,BH), 128x128 tile, 4 waves of 64x64.
// Epilogue: LDS transpose (64x132 fp32, union'd with staging) -> contiguous
// nontemporal dwordx4 stores (two 512B row segments per inst).
__global__ __launch_bounds__(256) void attn_kernel(float* __restrict__ dout) {
    __shared__ __align__(16) char smem[64*132*4];   // 33792 B >= 32 KB staging
    short* Qs = (short*)smem;                        // 16 KB
    short* Ks = (short*)(smem + 16384);              // 16 KB
    float* Ts = (float*)smem;                        // 64x132 fp32 transpose buffer

    int bh = blockIdx.z;
    int m0 = blockIdx.x * 128, n0 = blockIdx.y * 128;
    int t = threadIdx.x, lane = t & 63, w = t >> 6;
    int l15 = lane & 15, quad = lane >> 4;
    int r_in = lane >> 3, gq = lane & 7;
    int scol = (gq ^ r_in) << 3;

    const short* qb = (const short*)g_Qbf + (size_t)bh * BHSTR;
    const short* kb = (const short*)g_Kbf + (size_t)bh * BHSTR;
#pragma unroll
    for (int ii = 0; ii < 4; ii++) {
        int i = w * 4 + ii;
        gl_lds16(qb + (size_t)(m0 + i*8 + r_in) * 64 + scol, &Qs[i * 512]);
        gl_lds16(kb + (size_t)(n0 + i*8 + r_in) * 64 + scol, &Ks[i * 512]);
    }
    __syncthreads();

    int wm = (w >> 1) * 64, wn = (w & 1) * 64;
    f32x4 acc[4][4];
    f32x4 z4 = {0.f, 0.f, 0.f, 0.f};
#pragma unroll
    for (int i = 0; i < 4; i++)
#pragma unroll
        for (int j = 0; j < 4; j++) acc[i][j] = z4;

#pragma unroll
    for (int ks = 0; ks < 2; ks++) {
        int kg = ks * 4 + quad;
        int sw = (kg ^ (l15 & 7)) << 3;
        short8 qa[4], kbf[4];
#pragma unroll
        for (int i = 0; i < 4; i++) qa[i]  = *(const short8*)&Qs[(wm + i*16 + l15) * 64 + sw];
#pragma unroll
        for (int j = 0; j < 4; j++) kbf[j] = *(const short8*)&Ks[(wn + j*16 + l15) * 64 + sw];
#pragma unroll
        for (int i = 0; i < 4; i++)
#pragma unroll
            for (int j = 0; j < 4; j++) acc[i][j] = mfma_bf16(qa[i], kbf[j], acc[i][j]);
    }

    float* outp = dout + OUT0 + (size_t)bh * NSEQ * NSEQ;
    int halfw = w >> 1;           // which row-half this wave's acc belongs to
    int l31 = lane & 31, lh = lane >> 5;

#pragma unroll
    for (int h = 0; h < 2; h++) {
        __syncthreads();          // staging/prior-pass reads complete before overwrite
        if (halfw == h) {
#pragma unroll
            for (int i = 0; i < 4; i++) {
#pragma unroll
                for (int r2 = 0; r2 < 4; r2++) {
                    int row_l = i*16 + quad*4 + r2;                 // 0..63 in half
                    float qiv = g_qinv[bh*NSEQ + m0 + h*64 + row_l];
#pragma unroll
                    for (int j = 0; j < 4; j++) {
                        F4 v; v.v = acc[i][j];
                        Ts[row_l*132 + wn + j*16 + l15] = v.f[r2] * qiv;
                    }
                }
            }
        }
        __syncthreads();
        // all 4 waves store 16 rows each, 2 rows (2x512B contiguous) per inst
#pragma unroll
        for (int rr = 0; rr < 8; rr++) {
            int row_l = w*16 + rr*2 + lh;
            f32x4 val = *(const f32x4*)&Ts[row_l*132 + l31*4];
            int grow = m0 + h*64 + row_l;
            __builtin_nontemporal_store(val, (f32x4*)(outp + (size_t)grow * NSEQ + n0 + l31*4));
        }
    }
}

// ---------------- KV[e,d] = sum_m Kbf[m,e]*V[m,d], fp32 atomic partials ----------------
__global__ __launch_bounds__(256) void kv_kernel() {
    __shared__ float Ks2[64*64], Vs[64*64];
    int bh = blockIdx.x >> 4, part = blockIdx.x & 15;
    int t = threadIdx.x, d = t & 63, e0 = (t >> 6) * 16;
    float accv[16];
#pragma unroll
    for (int i = 0; i < 16; i++) accv[i] = 0.f;
    int sr = t >> 2, sc = (t & 3) * 16;
    for (int c = 0; c < 2; c++) {
        int nbase = part * 128 + c * 64;
        const unsigned short* kgp = g_Kbf + (size_t)bh * BHSTR + (size_t)(nbase + sr) * 64 + sc;
        const float* vgp = g_Vf + (size_t)bh * BHSTR + (size_t)(nbase + sr) * 64 + sc;
        S8 k0, k1;
        k0.v = *(const short8*)(kgp);
        k1.v = *(const short8*)(kgp + 8);
#pragma unroll
        for (int i = 0; i < 8; i++) Ks2[sr*64 + sc + i]     = bf2f((unsigned short)k0.s[i]);
#pragma unroll
        for (int i = 0; i < 8; i++) Ks2[sr*64 + sc + 8 + i] = bf2f((unsigned short)k1.s[i]);
#pragma unroll
        for (int i = 0; i < 4; i++) *(f32x4*)&Vs[sr*64 + sc + 4*i] = *(const f32x4*)(vgp + 4*i);
        __syncthreads();
#pragma unroll 4
        for (int m = 0; m < 64; m++) {
            float v = Vs[m*64 + d];
            const f32x4* kr = (const f32x4*)&Ks2[m*64 + e0];
            F4 q0, q1, q2, q3;
            q0.v = kr[0]; q1.v = kr[1]; q2.v = kr[2]; q3.v = kr[3];
#pragma unroll
            for (int i = 0; i < 4; i++) accv[i]      += q0.f[i] * v;
#pragma unroll
            for (int i = 0; i < 4; i++) accv[4 + i]  += q1.f[i] * v;
#pragma unroll
            for (int i = 0; i < 4; i++) accv[8 + i]  += q2.f[i] * v;
#pragma unroll
            for (int i = 0; i < 4; i++) accv[12 + i] += q3.f[i] * v;
        }
        __syncthreads();
    }
#pragma unroll
    for (int i = 0; i < 16; i++)
        atomicAdd(&g_KV[bh*4096 + (e0 + i)*64 + d], accv[i]);
}

// ---------------- out-heads: OHbf = bf16( qinv * Qbf @ KV ) ----------------
__global__ __launch_bounds__(256) void oh_kernel() {
    __shared__ float Qs2[128*64];
    __shared__ float KVs[64*64];
    int bh = blockIdx.y, r0 = blockIdx.x * 128;
    int t = threadIdx.x, d = t & 63, w = t >> 6;
    {
        int r = t >> 2, c = (t & 3) * 16;
        const float* s = g_KV + bh*4096 + r*64 + c;
#pragma unroll
        for (int i = 0; i < 4; i++) *(f32x4*)&KVs[r*64 + c + 4*i] = *(const f32x4*)(s + 4*i);
    }
    {
        int r = t >> 1, c = (t & 1) * 32;
        const unsigned short* s = g_Qbf + (size_t)bh * BHSTR + (size_t)(r0 + r) * 64 + c;
#pragma unroll
        for (int i = 0; i < 4; i++) {
            S8 x; x.v = *(const short8*)(s + 8*i);
#pragma unroll
            for (int j = 0; j < 8; j++) Qs2[r*64 + c + 8*i + j] = bf2f((unsigned short)x.s[j]);
        }
    }
    __syncthreads();
    float kvc[64];
#pragma unroll
    for (int e = 0; e < 64; e++) kvc[e] = KVs[e*64 + d];
    int b = bh >> 3, h = bh & 7;
    for (int rr = 0; rr < 32; rr++) {
        int row = w * 32 + rr;
        const f32x4* qr = (const f32x4*)&Qs2[row*64];
        float a = 0.f;
#pragma unroll
        for (int e4 = 0; e4 < 16; e4++) {
            F4 q; q.v = qr[e4];
            a += q.f[0]*kvc[4*e4] + q.f[1]*kvc[4*e4+1] + q.f[2]*kvc[4*e4+2] + q.f[3]*kvc[4*e4+3];
        }
        int grow = r0 + row;
        float val = a * g_qinv[bh*NSEQ + grow];
        g_OHbf[((size_t)b*NSEQ + grow)*512 + h*64 + d] = (short)f2bf(val);
    }
}

// ---------------- launch ----------------
extern "C" void kernel_launch(void* const* d_in, const int* in_sizes, int n_in,
                              void* d_out, int out_size, void* d_ws, size_t ws_size,
                              hipStream_t stream) {
    const float* q  = (const float*)d_in[0];
    const float* k  = (const float*)d_in[1];
    const float* v  = (const float*)d_in[2];
    const float* Wq = (const float*)d_in[3];
    const float* bq = (const float*)d_in[4];
    const float* Wk = (const float*)d_in[5];
    const float* bk = (const float*)d_in[6];
    const float* Wv = (const float*)d_in[7];
    const float* bv = (const float*)d_in[8];
    const float* Wo = (const float*)d_in[9];
    const float* bo = (const float*)d_in[10];
    float* out = (float*)d_out;

    prep_kernel<<<3584, 256, 0, stream>>>(q, k, v, Wq, Wk, Wv, Wo);

    dim3 gproj(32, 8);
    gemm_bf16<1><<<gproj, 256, 0, stream>>>(bk, nullptr, 1);   // K (produces ksum)
    gemm_bf16<1><<<gproj, 256, 0, stream>>>(bq, nullptr, 0);   // Q (consumes ksum)
    gemm_bf16<0><<<gproj, 256, 0, stream>>>(bv, nullptr, 2);   // V

    attn_kernel<<<dim3(16, 16, BH), 256, 0, stream>>>(out);

    kv_kernel<<<256, 256, 0, stream>>>();
    oh_kernel<<<dim3(16, BH), 256, 0, stream>>>();

    gemm_bf16<0><<<gproj, 256, 0, stream>>>(bo, out, 3);       // final projection
}